// Round 1
// baseline (649.478 us; speedup 1.0000x reference)
//
#include <hip/hip_runtime.h>
#include <math.h>

// Scattering net: four-step register FFT (128 = 16 reg-DFT x 8 cross-group DFT).
// Thread (g=tid>>7, q=tid&127) owns 16 elements x[q][g+8m] of each line.
// Spectral storage permutation per axis: k = k1 + 16*k2 -> position p = 8*k1 + k2.
// psi pre-permuted into this layout (both axes) with 1/16384 folded in.
//
// Round-12: PACKED FP32. k_scat_b is VALU-issue-bound (HBM 8%, conflicts 0,
// occupancy 88%). All complex arithmetic rewritten on v2f32 (ext_vector) so
// gfx950's packed-fp32 pipe (v_pk_fma_f32/v_pk_add_f32, 2 flops/lane/instr)
// halves the butterfly/cmult instruction count; bf16 pack collapses from
// 3 int ops to one v_cvt_pk_bf16_f32. Structure (grid, LDS layout, barriers,
// 66KB -> 2 blocks/CU) deliberately unchanged (r10/r11 lesson: residency is
// the binding resource).

#define SDIM 128
#define PLANE 16384
#define PITCH 129            // in storage elements
#define NT 1024
#define TWO_PI 6.28318530717958647692f

typedef float f32x2 __attribute__((ext_vector_type(2)));

__device__ __forceinline__ f32x2 mk2(float a, float b) { f32x2 r; r.x = a; r.y = b; return r; }

constexpr float W16R[8] = {1.f, 0.9238795325f, 0.7071067812f, 0.3826834324f,
                           0.f, -0.3826834324f, -0.7071067812f, -0.9238795325f};
constexpr float W16I[8] = {0.f, -0.3826834324f, -0.7071067812f, -0.9238795325f,
                           -1.f, -0.9238795325f, -0.7071067812f, -0.3826834324f};

// ---- packed bf16 complex <-> fp32 pair ----
// v_cvt_pk_bf16_f32: D.lo = bf16(S0), D.hi = bf16(S1). Storage: re in hi, im in lo.
__device__ __forceinline__ unsigned packbf(float re, float im) {
  unsigned r;
  asm("v_cvt_pk_bf16_f32 %0, %1, %2" : "=v"(r) : "v"(im), "v"(re));
  return r;
}
__device__ __forceinline__ f32x2 unpackbf(unsigned u) {
  return mk2(__uint_as_float(u & 0xFFFF0000u), __uint_as_float(u << 16));
}

// complex multiply u*v as two packed fma: (ux vx - uy vy, ux vy + uy vx)
__device__ __forceinline__ f32x2 cmul(f32x2 u, f32x2 v) {
  return u * v.x + u.yx * mk2(-v.y, v.y);
}

// storage-polymorphic LDS access
__device__ __forceinline__ void stC(float2* s, int idx, f32x2 c) { s[idx] = make_float2(c.x, c.y); }
__device__ __forceinline__ f32x2 ldC(const float2* s, int idx) { const float2 v = s[idx]; return mk2(v.x, v.y); }
__device__ __forceinline__ void stC(unsigned* s, int idx, f32x2 c) { s[idx] = packbf(c.x, c.y); }
__device__ __forceinline__ f32x2 ldC(const unsigned* s, int idx) { return unpackbf(s[idx]); }

// butterfly with w = W16^idx (idx compile-time constant after unroll).
template<bool INV>
__device__ __forceinline__ void bfly(f32x2& a, f32x2& b, const int idx) {
  f32x2 t;
  if (idx == 0) {                       // w = 1
    t = b;
  } else if (idx == 4) {                // w = -i (fwd) / +i (inv)
    t = INV ? mk2(-b.y, b.x) : mk2(b.y, -b.x);
  } else {
    const float wr = W16R[idx];
    const float wi = INV ? -W16I[idx] : W16I[idx];
    t = b * wr + b.yx * mk2(-wi, wi);
  }
  const f32x2 nb = a - t;
  a = a + t;
  b = nb;
}

#define CSWAP(x, a, b) { const f32x2 _t = x[a]; x[a] = x[b]; x[b] = _t; }

template<bool INV>
__device__ __forceinline__ void dft16(f32x2* x) {
  CSWAP(x, 1, 8) CSWAP(x, 2, 4) CSWAP(x, 3, 12)
  CSWAP(x, 5, 10) CSWAP(x, 7, 14) CSWAP(x, 11, 13)
#pragma unroll
  for (int ls = 1; ls <= 4; ++ls) {
    const int len = 1 << ls, half = len >> 1, tstep = 16 >> ls;
#pragma unroll
    for (int blk = 0; blk < 16; blk += len)
#pragma unroll
      for (int j = 0; j < half; ++j)
        bfly<INV>(x[blk + j], x[blk + j + half], j * tstep);
  }
}

template<bool INV>
__device__ __forceinline__ void dft8(f32x2* x) {
  CSWAP(x, 1, 4) CSWAP(x, 3, 6)
#pragma unroll
  for (int ls = 1; ls <= 3; ++ls) {
    const int len = 1 << ls, half = len >> 1, tstep = 8 >> ls;
#pragma unroll
    for (int blk = 0; blk < 8; blk += len)
#pragma unroll
      for (int j = 0; j < half; ++j)
        bfly<INV>(x[blk + j], x[blk + j + half], j * tstep * 2);
  }
}

// tw points at sTw + 16*g (LDS, wave-uniform -> broadcast). tw[0]=1: skip k=0.
__device__ __forceinline__ void twmul_fwd(f32x2* X, const float2* tw) {
#pragma unroll
  for (int k = 1; k < 16; ++k) {
    const float2 w = tw[k];
    X[k] = X[k] * w.x + X[k].yx * mk2(-w.y, w.y);
  }
}
__device__ __forceinline__ void twmul_inv(f32x2* X, const float2* tw) {
#pragma unroll
  for (int k = 1; k < 16; ++k) {
    const float2 w = tw[k];
    X[k] = X[k] * w.x + X[k].yx * mk2(w.y, -w.y);
  }
}

// Forward fft2. In: x regs, X[m] = row q element (g+8m).
// Out: col-spectral regs: X[k2] <-> plane pos (16g+k2, q), X[8+k2] <-> (16g+8+k2, q).
template<typename S>
__device__ __forceinline__ void fwd_fft2(f32x2* X, S* sC, int g, int q, const float2* tw) {
  const int rb = q * PITCH;
  dft16<false>(X);
  twmul_fwd(X, tw);
  __syncthreads();                             // B0
#pragma unroll
  for (int k = 0; k < 16; ++k) stC(sC, rb + 8 * k + g, X[k]);
  __syncthreads();                             // B1
#pragma unroll
  for (int t = 0; t < 8; ++t) {
    X[t] = ldC(sC, rb + 16 * g + t);
    X[8 + t] = ldC(sC, rb + 16 * g + 8 + t);
  }
  dft8<false>(X); dft8<false>(X + 8);
#pragma unroll
  for (int k2 = 0; k2 < 8; ++k2) {             // same cells: no barrier
    stC(sC, rb + 16 * g + k2, X[k2]);
    stC(sC, rb + 16 * g + 8 + k2, X[8 + k2]);
  }
  __syncthreads();                             // B2
#pragma unroll
  for (int m = 0; m < 16; ++m) X[m] = ldC(sC, (g + 8 * m) * PITCH + q);
  dft16<false>(X);
  twmul_fwd(X, tw);
#pragma unroll
  for (int k = 0; k < 16; ++k) stC(sC, (8 * k + g) * PITCH + q, X[k]);  // same cells
  __syncthreads();                             // B3
#pragma unroll
  for (int t = 0; t < 8; ++t) {
    X[t] = ldC(sC, (16 * g + t) * PITCH + q);
    X[8 + t] = ldC(sC, (16 * g + 8 + t) * PITCH + q);
  }
  dft8<false>(X); dft8<false>(X + 8);
}

// Inverse fft2 (unscaled; psi carries 1/16384). In: col-spectral regs.
// Out: x regs, X[m] = row q elem (g+8m). FIRST=true: no prior LDS consumers -> skip B0.
template<bool FIRST, typename S>
__device__ __forceinline__ void inv_fft2(f32x2* X, S* sC, int g, int q, const float2* tw) {
  dft8<true>(X); dft8<true>(X + 8);
  if constexpr (!FIRST) __syncthreads();       // B0
#pragma unroll
  for (int t = 0; t < 8; ++t) {
    stC(sC, (16 * g + t) * PITCH + q, X[t]);
    stC(sC, (16 * g + 8 + t) * PITCH + q, X[8 + t]);
  }
  __syncthreads();                             // B1
#pragma unroll
  for (int k = 0; k < 16; ++k) X[k] = ldC(sC, (8 * k + g) * PITCH + q);
  twmul_inv(X, tw);
  dft16<true>(X);
#pragma unroll
  for (int m = 0; m < 16; ++m) stC(sC, (g + 8 * m) * PITCH + q, X[m]);  // same cells
  __syncthreads();                             // B2
  const int rb = q * PITCH;
#pragma unroll
  for (int k2 = 0; k2 < 8; ++k2) {
    X[k2] = ldC(sC, rb + 16 * g + k2);
    X[8 + k2] = ldC(sC, rb + 16 * g + 8 + k2);
  }
  dft8<true>(X); dft8<true>(X + 8);
#pragma unroll
  for (int t = 0; t < 8; ++t) {                // same cells: no barrier
    stC(sC, rb + 16 * g + t, X[t]);
    stC(sC, rb + 16 * g + 8 + t, X[8 + t]);
  }
  __syncthreads();                             // B3
#pragma unroll
  for (int k = 0; k < 16; ++k) X[k] = ldC(sC, rb + 8 * k + g);
  twmul_inv(X, tw);
  dft16<true>(X);
}

__device__ __forceinline__ float block_reduce_sum(float v, float* red, int tid) {
#pragma unroll
  for (int o = 32; o > 0; o >>= 1) v += __shfl_down(v, o);
  __syncthreads();
  if ((tid & 63) == 0) red[tid >> 6] = v;
  __syncthreads();
  float t = 0.0f;
  if (tid == 0) {
#pragma unroll
    for (int w = 0; w < 16; ++w) t += red[w];
  }
  return t;
}

// psi in sigma x sigma spectral-position layout, 1/16384 folded in.
// Block 0 also fills the w128^{g*k} twiddle table into twg.
__global__ __launch_bounds__(256) void k_psi(const float* __restrict__ mags,
                                             const float* __restrict__ phases,
                                             float2* __restrict__ psi,
                                             float2* __restrict__ twg) {
  if (blockIdx.x == 0 && threadIdx.x < 128) {
    const int gg = threadIdx.x >> 4, k = threadIdx.x & 15;
    float sn, cs;
    __sincosf(-TWO_PI * (float)(gg * k) * (1.0f / 128.0f), &sn, &cs);
    twg[threadIdx.x] = make_float2(cs, sn);
  }
  const int gid = blockIdx.x * 256 + threadIdx.x;      // < 24*16384
  const int p = gid >> 14;
  const int pos = gid & (PLANE - 1);
  const int pr = pos >> 7, pc = pos & 127;
  const int kr = (pr >> 3) + 16 * (pr & 7);            // sigma^-1
  const int kc = (pc >> 3) + 16 * (pc & 7);
  const int src = (p << 14) + kr * SDIM + kc;
  const float m = mags[src] * (1.0f / 16384.0f);
  float sn, cs;
  __sincosf(phases[src], &sn, &cs);
  psi[gid] = make_float2(m * cs, m * sn);
}

// fp32 LDS: Xf feeds everything downstream; this kernel is ~5 us.
__global__ __launch_bounds__(NT) void k_img_fft(const float* __restrict__ img,
                                                float2* __restrict__ Xf,
                                                float* __restrict__ s0,
                                                const float2* __restrict__ twg) {
  __shared__ float2 sC[SDIM * PITCH];
  __shared__ float2 sTw[128];
  __shared__ float red[16];
  const int tid = threadIdx.x, b = blockIdx.x;
  const int g = tid >> 7, q = tid & 127;
  if (tid < 128) sTw[tid] = twg[tid];
  const float2* tw = sTw + 16 * g;
  const float* ip = img + b * PLANE;
  float sum = 0.0f;
#pragma unroll
  for (int kk = 0; kk < 16; ++kk) {
    const int e = tid + kk * NT;
    const float v = ip[e];
    sC[(e >> 7) * PITCH + (e & 127)] = make_float2(v, 0.0f);
    sum += v;
  }
  const float tot = block_reduce_sum(sum, red, tid);   // syncs publish sC & sTw
  if (tid == 0) s0[b] = tot * (1.0f / 16384.0f);
  __syncthreads();
  f32x2 X[16];
#pragma unroll
  for (int m = 0; m < 16; ++m) X[m] = mk2(sC[q * PITCH + g + 8 * m].x, 0.0f);
  fwd_fft2(X, sC, g, q, tw);
  float2* xp = Xf + b * PLANE;
#pragma unroll
  for (int k2 = 0; k2 < 8; ++k2) {
    const int p1 = (16 * g + k2) * SDIM + q;
    const int p2 = p1 + 8 * SDIM;
    xp[p1] = make_float2(X[k2].x, X[k2].y);
    xp[p2] = make_float2(X[8 + k2].x, X[8 + k2].y);
  }
}

// Phase A: bid<1280: (j1=bid>>8, b=(bid&255)>>2, l1=bid&3):
//   u1=|ifft2(Xf.psi1)|, U=fft2(u1) -> Ubuf (packbf) + s1. bid>=1280: s1 j=5.
__global__ __launch_bounds__(NT) void k_scat_a(const float2* __restrict__ Xf,
                                               const float2* __restrict__ psi,
                                               float* __restrict__ s1num,
                                               unsigned* __restrict__ Ubuf,
                                               const float2* __restrict__ twg) {
  __shared__ unsigned sU[SDIM * PITCH];        // 66 KB -> 2 blocks/CU
  __shared__ float2 sTw[128];
  __shared__ float red[16];
  const int tid = threadIdx.x;
  const int g = tid >> 7, q = tid & 127;
  if (tid < 128) sTw[tid] = twg[tid];
  const float2* tw = sTw + 16 * g;
  const int bid = blockIdx.x;
  f32x2 X[16];

  if (bid < 1280) {
    const int j1 = bid >> 8;
    const int b = (bid & 255) >> 2;
    const int l1 = bid & 3;
    const float2* xp = Xf + b * PLANE;
    const float2* pp = psi + (j1 * 4 + l1) * PLANE;
#pragma unroll
    for (int k2 = 0; k2 < 8; ++k2) {
      const int p1 = (16 * g + k2) * SDIM + q;
      const int p2 = p1 + 8 * SDIM;
      const float2 x1 = xp[p1], v1 = pp[p1];
      const float2 x2 = xp[p2], v2 = pp[p2];
      X[k2] = cmul(mk2(x1.x, x1.y), mk2(v1.x, v1.y));
      X[8 + k2] = cmul(mk2(x2.x, x2.y), mk2(v2.x, v2.y));
    }
    inv_fft2<true>(X, sU, g, q, tw);
    float s1sum = 0.0f;
#pragma unroll
    for (int m = 0; m < 16; ++m) {
      const f32x2 sq = X[m] * X[m];
      const float a = sqrtf(sq.x + sq.y);
      s1sum += a; X[m] = mk2(a, 0.0f);
    }
    fwd_fft2(X, sU, g, q, tw);
    unsigned* up = Ubuf + (size_t)((b * 5 + j1) * 4 + l1) * PLANE;
#pragma unroll
    for (int k2 = 0; k2 < 8; ++k2) {
      const int p1 = (16 * g + k2) * SDIM + q;
      const int p2 = p1 + 8 * SDIM;
      up[p1] = packbf(X[k2].x, X[k2].y);
      up[p2] = packbf(X[8 + k2].x, X[8 + k2].y);
    }
    const float tot = block_reduce_sum(s1sum, red, tid);
    if (tid == 0) atomicAdd(&s1num[b * 6 + j1], tot);
  } else {
    const int idx = bid - 1280;
    const int b = idx >> 2, l = idx & 3;
    const float2* xp = Xf + b * PLANE;
    const float2* pp = psi + (20 + l) * PLANE;
#pragma unroll
    for (int k2 = 0; k2 < 8; ++k2) {
      const int p1 = (16 * g + k2) * SDIM + q;
      const int p2 = p1 + 8 * SDIM;
      const float2 x1 = xp[p1], v1 = pp[p1];
      const float2 x2 = xp[p2], v2 = pp[p2];
      X[k2] = cmul(mk2(x1.x, x1.y), mk2(v1.x, v1.y));
      X[8 + k2] = cmul(mk2(x2.x, x2.y), mk2(v2.x, v2.y));
    }
    inv_fft2<true>(X, sU, g, q, tw);
    float s = 0.0f;
#pragma unroll
    for (int m = 0; m < 16; ++m) {
      const f32x2 sq = X[m] * X[m];
      s += sqrtf(sq.x + sq.y);
    }
    const float tot = block_reduce_sum(s, red, tid);
    if (tid == 0) atomicAdd(&s1num[b * 6 + 5], tot);
  }
}

// Phase B: one inner ifft per block. 15360 blocks (r9 structure: VGPR 32,
// 2 blocks/CU, 87% occupancy -- do NOT hoist U into regs, r10 regression).
// idx -> l2 = idx&3; t = idx>>2; pair = t%15; t/=15; l1 = t&3; b = t>>2.
__global__ __launch_bounds__(NT) void k_scat_b(const float2* __restrict__ psi,
                                               const unsigned* __restrict__ Ubuf,
                                               float* __restrict__ s2num,
                                               const float2* __restrict__ twg) {
  __shared__ unsigned sU[SDIM * PITCH];        // 66 KB -> 2 blocks/CU
  __shared__ float2 sTw[128];
  __shared__ float red[16];
  const int tid = threadIdx.x;
  const int g = tid >> 7, q = tid & 127;
  if (tid < 128) sTw[tid] = twg[tid];
  const float2* tw = sTw + 16 * g;
  int t = blockIdx.x;
  const int l2 = t & 3; t >>= 2;
  const int pair = t % 15; t /= 15;
  const int l1 = t & 3;
  const int b = t >> 2;
  int j1 = 0, base = 0;
  if (pair >= 14)      { j1 = 4; base = 14; }
  else if (pair >= 12) { j1 = 3; base = 12; }
  else if (pair >= 9)  { j1 = 2; base = 9; }
  else if (pair >= 5)  { j1 = 1; base = 5; }
  const int j2 = j1 + 1 + (pair - base);
  const unsigned* up = Ubuf + (size_t)((b * 5 + j1) * 4 + l1) * PLANE;
  const float2* pp = psi + (j2 * 4 + l2) * PLANE;
  f32x2 X[16];
#pragma unroll
  for (int k2 = 0; k2 < 8; ++k2) {
    const int p1 = (16 * g + k2) * SDIM + q;
    const int p2 = p1 + 8 * SDIM;
    const f32x2 u1 = unpackbf(up[p1]);
    const f32x2 u2 = unpackbf(up[p2]);
    const float2 v1 = pp[p1], v2 = pp[p2];
    X[k2] = cmul(u1, mk2(v1.x, v1.y));
    X[8 + k2] = cmul(u2, mk2(v2.x, v2.y));
  }
  inv_fft2<true>(X, sU, g, q, tw);
  float vsum = 0.0f;
#pragma unroll
  for (int m = 0; m < 16; ++m) {
    const f32x2 sq = X[m] * X[m];
    vsum += sqrtf(sq.x + sq.y);
  }
  const float tot = block_reduce_sum(vsum, red, tid);
  if (tid == 0) atomicAdd(&s2num[b * 15 + pair], tot);
}

// Fallback (ws too small): monolithic, U held in regs (will spill; correctness only).
__global__ __launch_bounds__(NT) void k_scat_mono(const float2* __restrict__ Xf,
                                                  const float2* __restrict__ psi,
                                                  float* __restrict__ s1num,
                                                  float* __restrict__ s2num,
                                                  const float2* __restrict__ twg) {
  __shared__ unsigned sU[SDIM * PITCH];
  __shared__ float2 sTw[128];
  __shared__ float red[16];
  const int tid = threadIdx.x;
  const int g = tid >> 7, q = tid & 127;
  if (tid < 128) sTw[tid] = twg[tid];
  const float2* tw = sTw + 16 * g;
  const int bid = blockIdx.x;
  f32x2 X[16];
  if (bid < 1280) {
    const int j1 = bid >> 8;
    const int b = (bid & 255) >> 2;
    const int l1 = bid & 3;
    const float2* xp = Xf + b * PLANE;
    const float2* pp = psi + (j1 * 4 + l1) * PLANE;
#pragma unroll
    for (int k2 = 0; k2 < 8; ++k2) {
      const int p1 = (16 * g + k2) * SDIM + q;
      const int p2 = p1 + 8 * SDIM;
      const float2 x1 = xp[p1], v1 = pp[p1];
      const float2 x2 = xp[p2], v2 = pp[p2];
      X[k2] = cmul(mk2(x1.x, x1.y), mk2(v1.x, v1.y));
      X[8 + k2] = cmul(mk2(x2.x, x2.y), mk2(v2.x, v2.y));
    }
    inv_fft2<true>(X, sU, g, q, tw);
    float s1sum = 0.0f;
#pragma unroll
    for (int m = 0; m < 16; ++m) {
      const f32x2 sq = X[m] * X[m];
      const float a = sqrtf(sq.x + sq.y);
      s1sum += a; X[m] = mk2(a, 0.0f);
    }
    fwd_fft2(X, sU, g, q, tw);
    f32x2 U[16];
#pragma unroll
    for (int k = 0; k < 16; ++k) U[k] = X[k];
    {
      const float tot = block_reduce_sum(s1sum, red, tid);
      if (tid == 0) atomicAdd(&s1num[b * 6 + j1], tot);
    }
    const int pb = (j1 * (11 - j1)) >> 1;
    int poff = (j1 + 1) * 4 * PLANE;
#pragma unroll 1
    for (int j2 = j1 + 1; j2 <= 5; ++j2) {
      float vsum = 0.0f;
#pragma unroll 1
      for (int l2 = 0; l2 < 4; ++l2) {
#pragma unroll
        for (int k2 = 0; k2 < 8; ++k2) {
          const int p1 = (16 * g + k2) * SDIM + q;
          const int p2i = p1 + 8 * SDIM;
          const float2 v1 = psi[poff + p1], v2 = psi[poff + p2i];
          X[k2] = cmul(U[k2], mk2(v1.x, v1.y));
          X[8 + k2] = cmul(U[8 + k2], mk2(v2.x, v2.y));
        }
        inv_fft2<false>(X, sU, g, q, tw);
#pragma unroll
        for (int m = 0; m < 16; ++m) {
          const f32x2 sq = X[m] * X[m];
          vsum += sqrtf(sq.x + sq.y);
        }
        poff += PLANE;
      }
      const float tot = block_reduce_sum(vsum, red, tid);
      if (tid == 0) atomicAdd(&s2num[b * 15 + pb + (j2 - j1 - 1)], tot);
    }
  } else {
    const int idx = bid - 1280;
    const int b = idx >> 2, l = idx & 3;
    const float2* xp = Xf + b * PLANE;
    const float2* pp = psi + (20 + l) * PLANE;
#pragma unroll
    for (int k2 = 0; k2 < 8; ++k2) {
      const int p1 = (16 * g + k2) * SDIM + q;
      const int p2 = p1 + 8 * SDIM;
      const float2 x1 = xp[p1], v1 = pp[p1];
      const float2 x2 = xp[p2], v2 = pp[p2];
      X[k2] = cmul(mk2(x1.x, x1.y), mk2(v1.x, v1.y));
      X[8 + k2] = cmul(mk2(x2.x, x2.y), mk2(v2.x, v2.y));
    }
    inv_fft2<true>(X, sU, g, q, tw);
    float s = 0.0f;
#pragma unroll
    for (int m = 0; m < 16; ++m) {
      const f32x2 sq = X[m] * X[m];
      s += sqrtf(sq.x + sq.y);
    }
    const float tot = block_reduce_sum(s, red, tid);
    if (tid == 0) atomicAdd(&s1num[b * 6 + 5], tot);
  }
}

__global__ __launch_bounds__(64) void k_final(const float* __restrict__ s0,
                                              const float* __restrict__ s1num,
                                              const float* __restrict__ s2num,
                                              const float* __restrict__ w1,
                                              const float* __restrict__ b1,
                                              const float* __restrict__ w2,
                                              const float* __restrict__ b2,
                                              const float* __restrict__ w3,
                                              const float* __restrict__ b3,
                                              float* __restrict__ out) {
  const int b = threadIdx.x;
  if (b >= 64) return;
  float x[22];
  x[0] = s0[b];
#pragma unroll
  for (int j = 0; j < 6; ++j) x[1 + j] = s1num[b * 6 + j] * (1.0f / (4.0f * 16384.0f));
#pragma unroll
  for (int p = 0; p < 15; ++p) x[7 + p] = s2num[b * 15 + p] * (1.0f / (16.0f * 16384.0f));
  float h1[16];
#pragma unroll
  for (int o = 0; o < 16; ++o) {
    float t = b1[o];
    for (int i = 0; i < 22; ++i) t += x[i] * w1[i * 16 + o];
    h1[o] = fmaxf(t, 0.0f);
  }
  float h2[16];
#pragma unroll
  for (int o = 0; o < 16; ++o) {
    float t = b2[o];
    for (int i = 0; i < 16; ++i) t += h1[i] * w2[i * 16 + o];
    h2[o] = fmaxf(t, 0.0f);
  }
  float t = b3[0];
#pragma unroll
  for (int i = 0; i < 16; ++i) t += h2[i] * w3[i];
  out[b] = 1.0f / (1.0f + expf(-t));
}

extern "C" void kernel_launch(void* const* d_in, const int* in_sizes, int n_in,
                              void* d_out, int out_size, void* d_ws, size_t ws_size,
                              hipStream_t stream) {
  (void)in_sizes; (void)n_in; (void)out_size;
  const float* image  = (const float*)d_in[0];
  const float* mags   = (const float*)d_in[1];
  const float* phases = (const float*)d_in[2];
  const float* w1 = (const float*)d_in[3];
  const float* b1 = (const float*)d_in[4];
  const float* w2 = (const float*)d_in[5];
  const float* b2 = (const float*)d_in[6];
  const float* w3 = (const float*)d_in[7];
  const float* b3 = (const float*)d_in[8];
  float* out = (float*)d_out;

  char* ws = (char*)d_ws;
  float2* psi = (float2*)ws;                       // 3,145,728 B
  float2* Xf  = (float2*)(ws + 3145728);           // 8,388,608 B
  float*  s0  = (float*)(ws + 11534336);           // 64
  float*  s1n = s0 + 64;                           // 384
  float*  s2n = s1n + 384;                         // 960
  float2* twg = (float2*)(s2n + 960);              // 128 float2
  unsigned* Ubuf = (unsigned*)(ws + 11542528);     // 83,886,080 B
  const size_t need = 11542528ull + 83886080ull;   // ~95.4 MB

  hipMemsetAsync(s1n, 0, (384 + 960) * sizeof(float), stream);
  k_psi<<<dim3(1536), dim3(256), 0, stream>>>(mags, phases, psi, twg);
  k_img_fft<<<dim3(64), dim3(NT), 0, stream>>>(image, Xf, s0, twg);
  if (ws_size >= need) {
    k_scat_a<<<dim3(1536), dim3(NT), 0, stream>>>(Xf, psi, s1n, Ubuf, twg);
    k_scat_b<<<dim3(15360), dim3(NT), 0, stream>>>(psi, Ubuf, s2n, twg);
  } else {
    k_scat_mono<<<dim3(1536), dim3(NT), 0, stream>>>(Xf, psi, s1n, s2n, twg);
  }
  k_final<<<dim3(1), dim3(64), 0, stream>>>(s0, s1n, s2n, w1, b1, w2, b2, w3, b3, out);
}

// Round 2
// 572.625 us; speedup vs baseline: 1.1342x; 1.1342x over previous
//
#include <hip/hip_runtime.h>
#include <math.h>

// Scattering net: four-step register FFT (128 = 16 reg-DFT x 8 cross-group DFT).
// Thread (g=tid>>7, q=tid&127) owns 16 elements x[q][g+8m] of each line.
// Spectral storage permutation per axis: k = k1 + 16*k2 -> position p = 8*k1 + k2.
// psi pre-permuted into this layout (both axes) with 1/16384 folded in.
//
// Round-13: TWIDDLES -> SGPRs. r12 (packed fp32) showed VALUBusy -31% with no
// time change: gfx950 pk_fp32 is issue-slot-only (157.3 TF peak = scalar rate),
// and the kernel is LDS-pipe-bound (~14k of 19k cyc/block on the CU's LDS unit:
// 96 data b32 + 30 wave-uniform twiddle b64 broadcasts per thread). Fix: revert
// to scalar fp32 (r11 known-good) and hoist the wave-uniform twiddle table
// (g = tid>>7 is constant per wave64) into SGPRs via readfirstlane from the
// global twg table. Removes all twiddle ds_reads + the sTw staging. Structure
// (grid, LDS layout, barriers, 66KB -> 2 blocks/CU) unchanged.

#define SDIM 128
#define PLANE 16384
#define PITCH 129            // in storage elements
#define NT 1024
#define TWO_PI 6.28318530717958647692f

constexpr float W16R[8] = {1.f, 0.9238795325f, 0.7071067812f, 0.3826834324f,
                           0.f, -0.3826834324f, -0.7071067812f, -0.9238795325f};
constexpr float W16I[8] = {0.f, -0.3826834324f, -0.7071067812f, -0.9238795325f,
                           -1.f, -0.9238795325f, -0.7071067812f, -0.3826834324f};

// ---- packed bf16 complex <-> fp32 pair ----
// round half up on both halves, then one v_perm_b32 picks {re[31:16], im[31:16]}.
__device__ __forceinline__ unsigned packbf(float re, float im) {
  const unsigned r = __float_as_uint(re) + 0x8000u;
  const unsigned i = __float_as_uint(im) + 0x8000u;
  return __builtin_amdgcn_perm(r, i, 0x07060302u);   // D = r.b3 r.b2 i.b3 i.b2
}
__device__ __forceinline__ void unpackbf(unsigned u, float& re, float& im) {
  re = __uint_as_float(u & 0xFFFF0000u);
  im = __uint_as_float(u << 16);
}

// storage-polymorphic LDS access
__device__ __forceinline__ void stC(float2* s, int idx, float re, float im) { s[idx] = make_float2(re, im); }
__device__ __forceinline__ void ldC(const float2* s, int idx, float& re, float& im) { const float2 v = s[idx]; re = v.x; im = v.y; }
__device__ __forceinline__ void stC(unsigned* s, int idx, float re, float im) { s[idx] = packbf(re, im); }
__device__ __forceinline__ void ldC(const unsigned* s, int idx, float& re, float& im) { unpackbf(s[idx], re, im); }

// wave-uniform twiddle table -> SGPRs. g = tid>>7 is wave-uniform (wave64).
// twg[16*g+k] = w128^{g*k}. readfirstlane pins the values scalar.
__device__ __forceinline__ void load_tw(const float2* __restrict__ twg, int g,
                                        float* twr, float* twi) {
#pragma unroll
  for (int k = 1; k < 16; ++k) {
    const float2 w = twg[16 * g + k];
    twr[k] = __uint_as_float(__builtin_amdgcn_readfirstlane(__float_as_uint(w.x)));
    twi[k] = __uint_as_float(__builtin_amdgcn_readfirstlane(__float_as_uint(w.y)));
  }
}

// butterfly with w = W16^idx (idx compile-time constant after unroll).
template<bool INV>
__device__ __forceinline__ void bfly(float& ar, float& ai, float& br, float& bi, const int idx) {
  float tr, ti;
  if (idx == 0) {                       // w = 1
    tr = br; ti = bi;
  } else if (idx == 4) {                // w = -i (fwd) / +i (inv)
    if (INV) { tr = -bi; ti = br; } else { tr = bi; ti = -br; }
  } else {
    const float wr = W16R[idx];
    const float wi = INV ? -W16I[idx] : W16I[idx];
    tr = br * wr - bi * wi;
    ti = br * wi + bi * wr;
  }
  br = ar - tr; bi = ai - ti;
  ar = ar + tr; ai = ai + ti;
}

#define CSWAP(re, im, a, b) { float _t = re[a]; re[a]=re[b]; re[b]=_t; _t = im[a]; im[a]=im[b]; im[b]=_t; }

template<bool INV>
__device__ __forceinline__ void dft16(float* re, float* im) {
  CSWAP(re, im, 1, 8) CSWAP(re, im, 2, 4) CSWAP(re, im, 3, 12)
  CSWAP(re, im, 5, 10) CSWAP(re, im, 7, 14) CSWAP(re, im, 11, 13)
#pragma unroll
  for (int ls = 1; ls <= 4; ++ls) {
    const int len = 1 << ls, half = len >> 1, tstep = 16 >> ls;
#pragma unroll
    for (int blk = 0; blk < 16; blk += len)
#pragma unroll
      for (int j = 0; j < half; ++j)
        bfly<INV>(re[blk + j], im[blk + j], re[blk + j + half], im[blk + j + half], j * tstep);
  }
}

template<bool INV>
__device__ __forceinline__ void dft8(float* re, float* im) {
  CSWAP(re, im, 1, 4) CSWAP(re, im, 3, 6)
#pragma unroll
  for (int ls = 1; ls <= 3; ++ls) {
    const int len = 1 << ls, half = len >> 1, tstep = 8 >> ls;
#pragma unroll
    for (int blk = 0; blk < 8; blk += len)
#pragma unroll
      for (int j = 0; j < half; ++j)
        bfly<INV>(re[blk + j], im[blk + j], re[blk + j + half], im[blk + j + half], j * tstep * 2);
  }
}

// twiddles from SGPRs: one scalar operand per VALU instr (legal encoding).
__device__ __forceinline__ void twmul_fwd(float* R, float* I, const float* twr, const float* twi) {
#pragma unroll
  for (int k = 1; k < 16; ++k) {
    const float r = R[k] * twr[k] - I[k] * twi[k];
    I[k] = R[k] * twi[k] + I[k] * twr[k]; R[k] = r;
  }
}
__device__ __forceinline__ void twmul_inv(float* R, float* I, const float* twr, const float* twi) {
#pragma unroll
  for (int k = 1; k < 16; ++k) {
    const float r = R[k] * twr[k] + I[k] * twi[k];
    I[k] = I[k] * twr[k] - R[k] * twi[k]; R[k] = r;
  }
}

// Forward fft2. In: x regs, R[m] = row q element (g+8m).
// Out: col-spectral regs: R[k2] <-> plane pos (16g+k2, q), R[8+k2] <-> (16g+8+k2, q).
template<typename S>
__device__ __forceinline__ void fwd_fft2(float* R, float* I, S* sC,
                                         int g, int q, const float* twr, const float* twi) {
  const int rb = q * PITCH;
  dft16<false>(R, I);
  twmul_fwd(R, I, twr, twi);
  __syncthreads();                             // B0
#pragma unroll
  for (int k = 0; k < 16; ++k) stC(sC, rb + 8 * k + g, R[k], I[k]);
  __syncthreads();                             // B1
#pragma unroll
  for (int t = 0; t < 8; ++t) {
    ldC(sC, rb + 16 * g + t, R[t], I[t]);
    ldC(sC, rb + 16 * g + 8 + t, R[8 + t], I[8 + t]);
  }
  dft8<false>(R, I); dft8<false>(R + 8, I + 8);
#pragma unroll
  for (int k2 = 0; k2 < 8; ++k2) {             // same cells: no barrier
    stC(sC, rb + 16 * g + k2, R[k2], I[k2]);
    stC(sC, rb + 16 * g + 8 + k2, R[8 + k2], I[8 + k2]);
  }
  __syncthreads();                             // B2
#pragma unroll
  for (int m = 0; m < 16; ++m) ldC(sC, (g + 8 * m) * PITCH + q, R[m], I[m]);
  dft16<false>(R, I);
  twmul_fwd(R, I, twr, twi);
#pragma unroll
  for (int k = 0; k < 16; ++k) stC(sC, (8 * k + g) * PITCH + q, R[k], I[k]);  // same cells
  __syncthreads();                             // B3
#pragma unroll
  for (int t = 0; t < 8; ++t) {
    ldC(sC, (16 * g + t) * PITCH + q, R[t], I[t]);
    ldC(sC, (16 * g + 8 + t) * PITCH + q, R[8 + t], I[8 + t]);
  }
  dft8<false>(R, I); dft8<false>(R + 8, I + 8);
}

// Inverse fft2 (unscaled; psi carries 1/16384). In: col-spectral regs.
// Out: x regs, R[m] = row q elem (g+8m). FIRST=true: no prior LDS consumers -> skip B0.
template<bool FIRST, typename S>
__device__ __forceinline__ void inv_fft2(float* R, float* I, S* sC,
                                         int g, int q, const float* twr, const float* twi) {
  dft8<true>(R, I); dft8<true>(R + 8, I + 8);
  if constexpr (!FIRST) __syncthreads();       // B0
#pragma unroll
  for (int t = 0; t < 8; ++t) {
    stC(sC, (16 * g + t) * PITCH + q, R[t], I[t]);
    stC(sC, (16 * g + 8 + t) * PITCH + q, R[8 + t], I[8 + t]);
  }
  __syncthreads();                             // B1
#pragma unroll
  for (int k = 0; k < 16; ++k) ldC(sC, (8 * k + g) * PITCH + q, R[k], I[k]);
  twmul_inv(R, I, twr, twi);
  dft16<true>(R, I);
#pragma unroll
  for (int m = 0; m < 16; ++m) stC(sC, (g + 8 * m) * PITCH + q, R[m], I[m]);  // same cells
  __syncthreads();                             // B2
  const int rb = q * PITCH;
#pragma unroll
  for (int k2 = 0; k2 < 8; ++k2) {
    ldC(sC, rb + 16 * g + k2, R[k2], I[k2]);
    ldC(sC, rb + 16 * g + 8 + k2, R[8 + k2], I[8 + k2]);
  }
  dft8<true>(R, I); dft8<true>(R + 8, I + 8);
#pragma unroll
  for (int t = 0; t < 8; ++t) {                // same cells: no barrier
    stC(sC, rb + 16 * g + t, R[t], I[t]);
    stC(sC, rb + 16 * g + 8 + t, R[8 + t], I[8 + t]);
  }
  __syncthreads();                             // B3
#pragma unroll
  for (int k = 0; k < 16; ++k) ldC(sC, rb + 8 * k + g, R[k], I[k]);
  twmul_inv(R, I, twr, twi);
  dft16<true>(R, I);
}

__device__ __forceinline__ float block_reduce_sum(float v, float* red, int tid) {
#pragma unroll
  for (int o = 32; o > 0; o >>= 1) v += __shfl_down(v, o);
  __syncthreads();
  if ((tid & 63) == 0) red[tid >> 6] = v;
  __syncthreads();
  float t = 0.0f;
  if (tid == 0) {
#pragma unroll
    for (int w = 0; w < 16; ++w) t += red[w];
  }
  return t;
}

// psi in sigma x sigma spectral-position layout, 1/16384 folded in.
// Block 0 also fills the w128^{g*k} twiddle table into twg.
__global__ __launch_bounds__(256) void k_psi(const float* __restrict__ mags,
                                             const float* __restrict__ phases,
                                             float2* __restrict__ psi,
                                             float2* __restrict__ twg) {
  if (blockIdx.x == 0 && threadIdx.x < 128) {
    const int gg = threadIdx.x >> 4, k = threadIdx.x & 15;
    float sn, cs;
    __sincosf(-TWO_PI * (float)(gg * k) * (1.0f / 128.0f), &sn, &cs);
    twg[threadIdx.x] = make_float2(cs, sn);
  }
  const int gid = blockIdx.x * 256 + threadIdx.x;      // < 24*16384
  const int p = gid >> 14;
  const int pos = gid & (PLANE - 1);
  const int pr = pos >> 7, pc = pos & 127;
  const int kr = (pr >> 3) + 16 * (pr & 7);            // sigma^-1
  const int kc = (pc >> 3) + 16 * (pc & 7);
  const int src = (p << 14) + kr * SDIM + kc;
  const float m = mags[src] * (1.0f / 16384.0f);
  float sn, cs;
  __sincosf(phases[src], &sn, &cs);
  psi[gid] = make_float2(m * cs, m * sn);
}

// fp32 LDS: Xf feeds everything downstream; this kernel is ~5 us.
__global__ __launch_bounds__(NT) void k_img_fft(const float* __restrict__ img,
                                                float2* __restrict__ Xf,
                                                float* __restrict__ s0,
                                                const float2* __restrict__ twg) {
  __shared__ float2 sC[SDIM * PITCH];
  __shared__ float red[16];
  const int tid = threadIdx.x, b = blockIdx.x;
  const int g = __builtin_amdgcn_readfirstlane(tid >> 7);
  const int q = tid & 127;
  float twr[16], twi[16];
  load_tw(twg, g, twr, twi);
  const float* ip = img + b * PLANE;
  float sum = 0.0f;
#pragma unroll
  for (int kk = 0; kk < 16; ++kk) {
    const int e = tid + kk * NT;
    const float v = ip[e];
    sC[(e >> 7) * PITCH + (e & 127)] = make_float2(v, 0.0f);
    sum += v;
  }
  const float tot = block_reduce_sum(sum, red, tid);   // syncs publish sC
  if (tid == 0) s0[b] = tot * (1.0f / 16384.0f);
  __syncthreads();
  float R[16], I[16];
#pragma unroll
  for (int m = 0; m < 16; ++m) { R[m] = sC[q * PITCH + g + 8 * m].x; I[m] = 0.0f; }
  fwd_fft2(R, I, sC, g, q, twr, twi);
  float2* xp = Xf + b * PLANE;
#pragma unroll
  for (int k2 = 0; k2 < 8; ++k2) {
    const int p1 = (16 * g + k2) * SDIM + q;
    const int p2 = p1 + 8 * SDIM;
    xp[p1] = make_float2(R[k2], I[k2]);
    xp[p2] = make_float2(R[8 + k2], I[8 + k2]);
  }
}

// Phase A: bid<1280: (j1=bid>>8, b=(bid&255)>>2, l1=bid&3):
//   u1=|ifft2(Xf.psi1)|, U=fft2(u1) -> Ubuf (packbf) + s1. bid>=1280: s1 j=5.
__global__ __launch_bounds__(NT) void k_scat_a(const float2* __restrict__ Xf,
                                               const float2* __restrict__ psi,
                                               float* __restrict__ s1num,
                                               unsigned* __restrict__ Ubuf,
                                               const float2* __restrict__ twg) {
  __shared__ unsigned sU[SDIM * PITCH];        // 66 KB -> 2 blocks/CU
  __shared__ float red[16];
  const int tid = threadIdx.x;
  const int g = __builtin_amdgcn_readfirstlane(tid >> 7);
  const int q = tid & 127;
  float twr[16], twi[16];
  load_tw(twg, g, twr, twi);
  const int bid = blockIdx.x;
  float R[16], I[16];

  if (bid < 1280) {
    const int j1 = bid >> 8;
    const int b = (bid & 255) >> 2;
    const int l1 = bid & 3;
    const float2* xp = Xf + b * PLANE;
    const float2* pp = psi + (j1 * 4 + l1) * PLANE;
#pragma unroll
    for (int k2 = 0; k2 < 8; ++k2) {
      const int p1 = (16 * g + k2) * SDIM + q;
      const int p2 = p1 + 8 * SDIM;
      const float2 x1 = xp[p1], v1 = pp[p1];
      const float2 x2 = xp[p2], v2 = pp[p2];
      R[k2] = x1.x * v1.x - x1.y * v1.y;     I[k2] = x1.x * v1.y + x1.y * v1.x;
      R[8 + k2] = x2.x * v2.x - x2.y * v2.y; I[8 + k2] = x2.x * v2.y + x2.y * v2.x;
    }
    inv_fft2<true>(R, I, sU, g, q, twr, twi);
    float s1sum = 0.0f;
#pragma unroll
    for (int m = 0; m < 16; ++m) {
      const float a = sqrtf(R[m] * R[m] + I[m] * I[m]);
      s1sum += a; R[m] = a; I[m] = 0.0f;
    }
    fwd_fft2(R, I, sU, g, q, twr, twi);
    unsigned* up = Ubuf + (size_t)((b * 5 + j1) * 4 + l1) * PLANE;
#pragma unroll
    for (int k2 = 0; k2 < 8; ++k2) {
      const int p1 = (16 * g + k2) * SDIM + q;
      const int p2 = p1 + 8 * SDIM;
      up[p1] = packbf(R[k2], I[k2]);
      up[p2] = packbf(R[8 + k2], I[8 + k2]);
    }
    const float tot = block_reduce_sum(s1sum, red, tid);
    if (tid == 0) atomicAdd(&s1num[b * 6 + j1], tot);
  } else {
    const int idx = bid - 1280;
    const int b = idx >> 2, l = idx & 3;
    const float2* xp = Xf + b * PLANE;
    const float2* pp = psi + (20 + l) * PLANE;
#pragma unroll
    for (int k2 = 0; k2 < 8; ++k2) {
      const int p1 = (16 * g + k2) * SDIM + q;
      const int p2 = p1 + 8 * SDIM;
      const float2 x1 = xp[p1], v1 = pp[p1];
      const float2 x2 = xp[p2], v2 = pp[p2];
      R[k2] = x1.x * v1.x - x1.y * v1.y;     I[k2] = x1.x * v1.y + x1.y * v1.x;
      R[8 + k2] = x2.x * v2.x - x2.y * v2.y; I[8 + k2] = x2.x * v2.y + x2.y * v2.x;
    }
    inv_fft2<true>(R, I, sU, g, q, twr, twi);
    float s = 0.0f;
#pragma unroll
    for (int m = 0; m < 16; ++m) s += sqrtf(R[m] * R[m] + I[m] * I[m]);
    const float tot = block_reduce_sum(s, red, tid);
    if (tid == 0) atomicAdd(&s1num[b * 6 + 5], tot);
  }
}

// Phase B: one inner ifft per block. 15360 blocks (r9 structure: VGPR 32,
// 2 blocks/CU, 2 blocks/CU residency is the binding resource -- do NOT hoist
// U into regs, r10 regression).
// idx -> l2 = idx&3; t = idx>>2; pair = t%15; t/=15; l1 = t&3; b = t>>2.
__global__ __launch_bounds__(NT) void k_scat_b(const float2* __restrict__ psi,
                                               const unsigned* __restrict__ Ubuf,
                                               float* __restrict__ s2num,
                                               const float2* __restrict__ twg) {
  __shared__ unsigned sU[SDIM * PITCH];        // 66 KB -> 2 blocks/CU
  __shared__ float red[16];
  const int tid = threadIdx.x;
  const int g = __builtin_amdgcn_readfirstlane(tid >> 7);
  const int q = tid & 127;
  float twr[16], twi[16];
  load_tw(twg, g, twr, twi);
  int t = blockIdx.x;
  const int l2 = t & 3; t >>= 2;
  const int pair = t % 15; t /= 15;
  const int l1 = t & 3;
  const int b = t >> 2;
  int j1 = 0, base = 0;
  if (pair >= 14)      { j1 = 4; base = 14; }
  else if (pair >= 12) { j1 = 3; base = 12; }
  else if (pair >= 9)  { j1 = 2; base = 9; }
  else if (pair >= 5)  { j1 = 1; base = 5; }
  const int j2 = j1 + 1 + (pair - base);
  const unsigned* up = Ubuf + (size_t)((b * 5 + j1) * 4 + l1) * PLANE;
  const float2* pp = psi + (j2 * 4 + l2) * PLANE;
  float R[16], I[16];
#pragma unroll
  for (int k2 = 0; k2 < 8; ++k2) {
    const int p1 = (16 * g + k2) * SDIM + q;
    const int p2 = p1 + 8 * SDIM;
    float ur1, ui1, ur2, ui2;
    unpackbf(up[p1], ur1, ui1);
    unpackbf(up[p2], ur2, ui2);
    const float2 v1 = pp[p1], v2 = pp[p2];
    R[k2] = ur1 * v1.x - ui1 * v1.y;     I[k2] = ur1 * v1.y + ui1 * v1.x;
    R[8 + k2] = ur2 * v2.x - ui2 * v2.y; I[8 + k2] = ur2 * v2.y + ui2 * v2.x;
  }
  inv_fft2<true>(R, I, sU, g, q, twr, twi);
  float vsum = 0.0f;
#pragma unroll
  for (int m = 0; m < 16; ++m) vsum += sqrtf(R[m] * R[m] + I[m] * I[m]);
  const float tot = block_reduce_sum(vsum, red, tid);
  if (tid == 0) atomicAdd(&s2num[b * 15 + pair], tot);
}

// Fallback (ws too small): monolithic, U held in regs (will spill; correctness only).
__global__ __launch_bounds__(NT) void k_scat_mono(const float2* __restrict__ Xf,
                                                  const float2* __restrict__ psi,
                                                  float* __restrict__ s1num,
                                                  float* __restrict__ s2num,
                                                  const float2* __restrict__ twg) {
  __shared__ unsigned sU[SDIM * PITCH];
  __shared__ float red[16];
  const int tid = threadIdx.x;
  const int g = __builtin_amdgcn_readfirstlane(tid >> 7);
  const int q = tid & 127;
  float twr[16], twi[16];
  load_tw(twg, g, twr, twi);
  const int bid = blockIdx.x;
  float R[16], I[16];
  if (bid < 1280) {
    const int j1 = bid >> 8;
    const int b = (bid & 255) >> 2;
    const int l1 = bid & 3;
    const float2* xp = Xf + b * PLANE;
    const float2* pp = psi + (j1 * 4 + l1) * PLANE;
#pragma unroll
    for (int k2 = 0; k2 < 8; ++k2) {
      const int p1 = (16 * g + k2) * SDIM + q;
      const int p2 = p1 + 8 * SDIM;
      const float2 x1 = xp[p1], v1 = pp[p1];
      const float2 x2 = xp[p2], v2 = pp[p2];
      R[k2] = x1.x * v1.x - x1.y * v1.y;     I[k2] = x1.x * v1.y + x1.y * v1.x;
      R[8 + k2] = x2.x * v2.x - x2.y * v2.y; I[8 + k2] = x2.x * v2.y + x2.y * v2.x;
    }
    inv_fft2<true>(R, I, sU, g, q, twr, twi);
    float s1sum = 0.0f;
#pragma unroll
    for (int m = 0; m < 16; ++m) {
      const float a = sqrtf(R[m] * R[m] + I[m] * I[m]);
      s1sum += a; R[m] = a; I[m] = 0.0f;
    }
    fwd_fft2(R, I, sU, g, q, twr, twi);
    float Ur[16], Ui[16];
#pragma unroll
    for (int k = 0; k < 16; ++k) { Ur[k] = R[k]; Ui[k] = I[k]; }
    {
      const float tot = block_reduce_sum(s1sum, red, tid);
      if (tid == 0) atomicAdd(&s1num[b * 6 + j1], tot);
    }
    const int pb = (j1 * (11 - j1)) >> 1;
    int poff = (j1 + 1) * 4 * PLANE;
#pragma unroll 1
    for (int j2 = j1 + 1; j2 <= 5; ++j2) {
      float vsum = 0.0f;
#pragma unroll 1
      for (int l2 = 0; l2 < 4; ++l2) {
#pragma unroll
        for (int k2 = 0; k2 < 8; ++k2) {
          const int p1 = (16 * g + k2) * SDIM + q;
          const int p2i = p1 + 8 * SDIM;
          const float2 v1 = psi[poff + p1], v2 = psi[poff + p2i];
          R[k2] = Ur[k2] * v1.x - Ui[k2] * v1.y;
          I[k2] = Ur[k2] * v1.y + Ui[k2] * v1.x;
          R[8 + k2] = Ur[8 + k2] * v2.x - Ui[8 + k2] * v2.y;
          I[8 + k2] = Ur[8 + k2] * v2.y + Ui[8 + k2] * v2.x;
        }
        inv_fft2<false>(R, I, sU, g, q, twr, twi);
#pragma unroll
        for (int m = 0; m < 16; ++m) vsum += sqrtf(R[m] * R[m] + I[m] * I[m]);
        poff += PLANE;
      }
      const float tot = block_reduce_sum(vsum, red, tid);
      if (tid == 0) atomicAdd(&s2num[b * 15 + pb + (j2 - j1 - 1)], tot);
    }
  } else {
    const int idx = bid - 1280;
    const int b = idx >> 2, l = idx & 3;
    const float2* xp = Xf + b * PLANE;
    const float2* pp = psi + (20 + l) * PLANE;
#pragma unroll
    for (int k2 = 0; k2 < 8; ++k2) {
      const int p1 = (16 * g + k2) * SDIM + q;
      const int p2 = p1 + 8 * SDIM;
      const float2 x1 = xp[p1], v1 = pp[p1];
      const float2 x2 = xp[p2], v2 = pp[p2];
      R[k2] = x1.x * v1.x - x1.y * v1.y;     I[k2] = x1.x * v1.y + x1.y * v1.x;
      R[8 + k2] = x2.x * v2.x - x2.y * v2.y; I[8 + k2] = x2.x * v2.y + x2.y * v2.x;
    }
    inv_fft2<true>(R, I, sU, g, q, twr, twi);
    float s = 0.0f;
#pragma unroll
    for (int m = 0; m < 16; ++m) s += sqrtf(R[m] * R[m] + I[m] * I[m]);
    const float tot = block_reduce_sum(s, red, tid);
    if (tid == 0) atomicAdd(&s1num[b * 6 + 5], tot);
  }
}

__global__ __launch_bounds__(64) void k_final(const float* __restrict__ s0,
                                              const float* __restrict__ s1num,
                                              const float* __restrict__ s2num,
                                              const float* __restrict__ w1,
                                              const float* __restrict__ b1,
                                              const float* __restrict__ w2,
                                              const float* __restrict__ b2,
                                              const float* __restrict__ w3,
                                              const float* __restrict__ b3,
                                              float* __restrict__ out) {
  const int b = threadIdx.x;
  if (b >= 64) return;
  float x[22];
  x[0] = s0[b];
#pragma unroll
  for (int j = 0; j < 6; ++j) x[1 + j] = s1num[b * 6 + j] * (1.0f / (4.0f * 16384.0f));
#pragma unroll
  for (int p = 0; p < 15; ++p) x[7 + p] = s2num[b * 15 + p] * (1.0f / (16.0f * 16384.0f));
  float h1[16];
#pragma unroll
  for (int o = 0; o < 16; ++o) {
    float t = b1[o];
    for (int i = 0; i < 22; ++i) t += x[i] * w1[i * 16 + o];
    h1[o] = fmaxf(t, 0.0f);
  }
  float h2[16];
#pragma unroll
  for (int o = 0; o < 16; ++o) {
    float t = b2[o];
    for (int i = 0; i < 16; ++i) t += h1[i] * w2[i * 16 + o];
    h2[o] = fmaxf(t, 0.0f);
  }
  float t = b3[0];
#pragma unroll
  for (int i = 0; i < 16; ++i) t += h2[i] * w3[i];
  out[b] = 1.0f / (1.0f + expf(-t));
}

extern "C" void kernel_launch(void* const* d_in, const int* in_sizes, int n_in,
                              void* d_out, int out_size, void* d_ws, size_t ws_size,
                              hipStream_t stream) {
  (void)in_sizes; (void)n_in; (void)out_size;
  const float* image  = (const float*)d_in[0];
  const float* mags   = (const float*)d_in[1];
  const float* phases = (const float*)d_in[2];
  const float* w1 = (const float*)d_in[3];
  const float* b1 = (const float*)d_in[4];
  const float* w2 = (const float*)d_in[5];
  const float* b2 = (const float*)d_in[6];
  const float* w3 = (const float*)d_in[7];
  const float* b3 = (const float*)d_in[8];
  float* out = (float*)d_out;

  char* ws = (char*)d_ws;
  float2* psi = (float2*)ws;                       // 3,145,728 B
  float2* Xf  = (float2*)(ws + 3145728);           // 8,388,608 B
  float*  s0  = (float*)(ws + 11534336);           // 64
  float*  s1n = s0 + 64;                           // 384
  float*  s2n = s1n + 384;                         // 960
  float2* twg = (float2*)(s2n + 960);              // 128 float2
  unsigned* Ubuf = (unsigned*)(ws + 11542528);     // 83,886,080 B
  const size_t need = 11542528ull + 83886080ull;   // ~95.4 MB

  hipMemsetAsync(s1n, 0, (384 + 960) * sizeof(float), stream);
  k_psi<<<dim3(1536), dim3(256), 0, stream>>>(mags, phases, psi, twg);
  k_img_fft<<<dim3(64), dim3(NT), 0, stream>>>(image, Xf, s0, twg);
  if (ws_size >= need) {
    k_scat_a<<<dim3(1536), dim3(NT), 0, stream>>>(Xf, psi, s1n, Ubuf, twg);
    k_scat_b<<<dim3(15360), dim3(NT), 0, stream>>>(psi, Ubuf, s2n, twg);
  } else {
    k_scat_mono<<<dim3(1536), dim3(NT), 0, stream>>>(Xf, psi, s1n, s2n, twg);
  }
  k_final<<<dim3(1), dim3(64), 0, stream>>>(s0, s1n, s2n, w1, b1, w2, b2, w3, b3, out);
}

// Round 3
// 521.407 us; speedup vs baseline: 1.2456x; 1.0982x over previous
//
#include <hip/hip_runtime.h>
#include <math.h>

// Scattering net: four-step register FFT (128 = 16 reg-DFT x 8 cross-group DFT).
// Thread (g=tid>>7, q=tid&127) owns 16 elements x[q][g+8m] of each line.
// Spectral storage permutation per axis: k = k1 + 16*k2 -> position p = 8*k1 + k2.
// psi pre-permuted into this layout (both axes) with 1/16384 folded in.
//
// Round-14: LDS PAIRING. r13 (SGPR twiddles) gained little on k_scat_b ->
// wave-uniform LDS reads were broadcast-cheap; the DATA exchanges are the LDS
// cost (~50% of round cycles, ~= VALU's 49%). The compiler only merges
// ds_read2/write2 when both offsets fit 8 bits from one base; the old
// [(row)*129+q] phases (spans 129t / 1032k) stayed scalar b32. Fix: store each
// column-exchange in a strip [q*129 + pos] (pure relabeling, same routing):
//   inv A-store D1 / A-load D8 / B-store D8 -> read2/write2 from base rb;
//   inv B-load / C-store -> per-pair bases with {0,+129} offsets;
//   only inv C-load (16 b32) + fwd B2-load/C-store stay scalar (span 1032).
// Also sqrtf -> __builtin_amdgcn_sqrtf (raw v_sqrt_f32, saves ~6-8 VALU each).
// Structure (grid, barriers, 66KB -> 2 blocks/CU, scalar fp32) unchanged.

#define SDIM 128
#define PLANE 16384
#define PITCH 129            // in storage elements
#define NT 1024
#define TWO_PI 6.28318530717958647692f

constexpr float W16R[8] = {1.f, 0.9238795325f, 0.7071067812f, 0.3826834324f,
                           0.f, -0.3826834324f, -0.7071067812f, -0.9238795325f};
constexpr float W16I[8] = {0.f, -0.3826834324f, -0.7071067812f, -0.9238795325f,
                           -1.f, -0.9238795325f, -0.7071067812f, -0.3826834324f};

__device__ __forceinline__ float fast_sqrtf(float x) {
  return __builtin_amdgcn_sqrtf(x);
}

// ---- packed bf16 complex <-> fp32 pair ----
// round half up on both halves, then one v_perm_b32 picks {re[31:16], im[31:16]}.
__device__ __forceinline__ unsigned packbf(float re, float im) {
  const unsigned r = __float_as_uint(re) + 0x8000u;
  const unsigned i = __float_as_uint(im) + 0x8000u;
  return __builtin_amdgcn_perm(r, i, 0x07060302u);   // D = r.b3 r.b2 i.b3 i.b2
}
__device__ __forceinline__ void unpackbf(unsigned u, float& re, float& im) {
  re = __uint_as_float(u & 0xFFFF0000u);
  im = __uint_as_float(u << 16);
}

// storage-polymorphic LDS access
__device__ __forceinline__ void stC(float2* s, int idx, float re, float im) { s[idx] = make_float2(re, im); }
__device__ __forceinline__ void ldC(const float2* s, int idx, float& re, float& im) { const float2 v = s[idx]; re = v.x; im = v.y; }
__device__ __forceinline__ void stC(unsigned* s, int idx, float re, float im) { s[idx] = packbf(re, im); }
__device__ __forceinline__ void ldC(const unsigned* s, int idx, float& re, float& im) { unpackbf(s[idx], re, im); }

// wave-uniform twiddle table -> SGPRs. g = tid>>7 is wave-uniform (wave64).
// twg[16*g+k] = w128^{g*k}. readfirstlane pins the values scalar.
__device__ __forceinline__ void load_tw(const float2* __restrict__ twg, int g,
                                        float* twr, float* twi) {
#pragma unroll
  for (int k = 1; k < 16; ++k) {
    const float2 w = twg[16 * g + k];
    twr[k] = __uint_as_float(__builtin_amdgcn_readfirstlane(__float_as_uint(w.x)));
    twi[k] = __uint_as_float(__builtin_amdgcn_readfirstlane(__float_as_uint(w.y)));
  }
}

// butterfly with w = W16^idx (idx compile-time constant after unroll).
template<bool INV>
__device__ __forceinline__ void bfly(float& ar, float& ai, float& br, float& bi, const int idx) {
  float tr, ti;
  if (idx == 0) {                       // w = 1
    tr = br; ti = bi;
  } else if (idx == 4) {                // w = -i (fwd) / +i (inv)
    if (INV) { tr = -bi; ti = br; } else { tr = bi; ti = -br; }
  } else {
    const float wr = W16R[idx];
    const float wi = INV ? -W16I[idx] : W16I[idx];
    tr = br * wr - bi * wi;
    ti = br * wi + bi * wr;
  }
  br = ar - tr; bi = ai - ti;
  ar = ar + tr; ai = ai + ti;
}

#define CSWAP(re, im, a, b) { float _t = re[a]; re[a]=re[b]; re[b]=_t; _t = im[a]; im[a]=im[b]; im[b]=_t; }

template<bool INV>
__device__ __forceinline__ void dft16(float* re, float* im) {
  CSWAP(re, im, 1, 8) CSWAP(re, im, 2, 4) CSWAP(re, im, 3, 12)
  CSWAP(re, im, 5, 10) CSWAP(re, im, 7, 14) CSWAP(re, im, 11, 13)
#pragma unroll
  for (int ls = 1; ls <= 4; ++ls) {
    const int len = 1 << ls, half = len >> 1, tstep = 16 >> ls;
#pragma unroll
    for (int blk = 0; blk < 16; blk += len)
#pragma unroll
      for (int j = 0; j < half; ++j)
        bfly<INV>(re[blk + j], im[blk + j], re[blk + j + half], im[blk + j + half], j * tstep);
  }
}

template<bool INV>
__device__ __forceinline__ void dft8(float* re, float* im) {
  CSWAP(re, im, 1, 4) CSWAP(re, im, 3, 6)
#pragma unroll
  for (int ls = 1; ls <= 3; ++ls) {
    const int len = 1 << ls, half = len >> 1, tstep = 8 >> ls;
#pragma unroll
    for (int blk = 0; blk < 8; blk += len)
#pragma unroll
      for (int j = 0; j < half; ++j)
        bfly<INV>(re[blk + j], im[blk + j], re[blk + j + half], im[blk + j + half], j * tstep * 2);
  }
}

// twiddles from SGPRs: one scalar operand per VALU instr (legal encoding).
__device__ __forceinline__ void twmul_fwd(float* R, float* I, const float* twr, const float* twi) {
#pragma unroll
  for (int k = 1; k < 16; ++k) {
    const float r = R[k] * twr[k] - I[k] * twi[k];
    I[k] = R[k] * twi[k] + I[k] * twr[k]; R[k] = r;
  }
}
__device__ __forceinline__ void twmul_inv(float* R, float* I, const float* twr, const float* twi) {
#pragma unroll
  for (int k = 1; k < 16; ++k) {
    const float r = R[k] * twr[k] + I[k] * twi[k];
    I[k] = I[k] * twr[k] - R[k] * twi[k]; R[k] = r;
  }
}

// Forward fft2. In: x regs, R[m] = row q element (g+8m).
// Out: col-spectral regs: R[k2] <-> plane pos (16g+k2, q), R[8+k2] <-> (16g+8+k2, q).
template<typename S>
__device__ __forceinline__ void fwd_fft2(float* R, float* I, S* sC,
                                         int g, int q, const float* twr, const float* twi) {
  const int rb = q * PITCH;
  dft16<false>(R, I);
  twmul_fwd(R, I, twr, twi);
  __syncthreads();                             // B0
#pragma unroll
  for (int k = 0; k < 16; ++k) stC(sC, rb + 8 * k + g, R[k], I[k]);   // D8 write2
  __syncthreads();                             // B1
#pragma unroll
  for (int t = 0; t < 8; ++t) {                                        // D1 read2
    ldC(sC, rb + 16 * g + t, R[t], I[t]);
    ldC(sC, rb + 16 * g + 8 + t, R[8 + t], I[8 + t]);
  }
  dft8<false>(R, I); dft8<false>(R + 8, I + 8);
#pragma unroll
  for (int k2 = 0; k2 < 8; ++k2) {             // same cells: no barrier; D1 write2
    stC(sC, rb + 16 * g + k2, R[k2], I[k2]);
    stC(sC, rb + 16 * g + 8 + k2, R[8 + k2], I[8 + k2]);
  }
  __syncthreads();                             // B2
#pragma unroll
  for (int m = 0; m < 16; ++m) ldC(sC, (g + 8 * m) * PITCH + q, R[m], I[m]);  // col b32
  dft16<false>(R, I);
  twmul_fwd(R, I, twr, twi);
#pragma unroll
  for (int k = 0; k < 16; ++k) stC(sC, (8 * k + g) * PITCH + q, R[k], I[k]);  // same cells, col b32
  __syncthreads();                             // B3
#pragma unroll
  for (int u = 0; u < 8; ++u) {                // per-pair base, offsets {0,+PITCH} -> read2
    const int bp = (16 * g + 2 * u) * PITCH + q;
    ldC(sC, bp, R[2 * u], I[2 * u]);
    ldC(sC, bp + PITCH, R[2 * u + 1], I[2 * u + 1]);
  }
  dft8<false>(R, I); dft8<false>(R + 8, I + 8);
}

// Inverse fft2 (unscaled; psi carries 1/16384). In: col-spectral regs.
// Out: x regs, R[m] = row q elem (g+8m). FIRST=true: no prior LDS consumers -> skip B0.
//
// Relabeled LDS (r14): column-q's exchange data lives in strip [q*PITCH + pos]
// (phases A/B, flipped convention cell[c*P + r] = V(r,c)); the transpose then
// reads [(16g+t)*P + q]. Routing identical to the old [(row)*P + q] scheme:
//   A: store V(16g+t, q) @ [q*P+16g+t], load V(8k+g, q) @ [q*P+8k+g]
//   B: store V2(g+8m, q) @ [q*P+g+8m] (same cells as A-load -> no barrier),
//      transpose-load V2(q, 16g+t) @ [(16g+t)*P+q]
//   C: store W(q,16g+t) @ same cells, load W(q,8k+g) @ [(8k+g)*P+q]
template<bool FIRST, typename S>
__device__ __forceinline__ void inv_fft2(float* R, float* I, S* sC,
                                         int g, int q, const float* twr, const float* twi) {
  const int rb = q * PITCH;
  dft8<true>(R, I); dft8<true>(R + 8, I + 8);
  if constexpr (!FIRST) __syncthreads();       // B0
#pragma unroll
  for (int t = 0; t < 16; ++t) stC(sC, rb + 16 * g + t, R[t], I[t]);  // D1 write2
  __syncthreads();                             // B1
#pragma unroll
  for (int k = 0; k < 16; ++k) ldC(sC, rb + 8 * k + g, R[k], I[k]);   // D8 read2
  twmul_inv(R, I, twr, twi);
  dft16<true>(R, I);
#pragma unroll
  for (int m = 0; m < 16; ++m) stC(sC, rb + g + 8 * m, R[m], I[m]);   // same cells; D8 write2
  __syncthreads();                             // B2
#pragma unroll
  for (int u = 0; u < 8; ++u) {                // transpose read; pair base {0,+PITCH}
    const int bp = (16 * g + 2 * u) * PITCH + q;
    ldC(sC, bp, R[2 * u], I[2 * u]);
    ldC(sC, bp + PITCH, R[2 * u + 1], I[2 * u + 1]);
  }
  dft8<true>(R, I); dft8<true>(R + 8, I + 8);
#pragma unroll
  for (int u = 0; u < 8; ++u) {                // same cells: no barrier; pair base write2
    const int bp = (16 * g + 2 * u) * PITCH + q;
    stC(sC, bp, R[2 * u], I[2 * u]);
    stC(sC, bp + PITCH, R[2 * u + 1], I[2 * u + 1]);
  }
  __syncthreads();                             // B3
#pragma unroll
  for (int k = 0; k < 16; ++k) ldC(sC, (8 * k + g) * PITCH + q, R[k], I[k]);  // col b32
  twmul_inv(R, I, twr, twi);
  dft16<true>(R, I);
}

__device__ __forceinline__ float block_reduce_sum(float v, float* red, int tid) {
#pragma unroll
  for (int o = 32; o > 0; o >>= 1) v += __shfl_down(v, o);
  __syncthreads();
  if ((tid & 63) == 0) red[tid >> 6] = v;
  __syncthreads();
  float t = 0.0f;
  if (tid == 0) {
#pragma unroll
    for (int w = 0; w < 16; ++w) t += red[w];
  }
  return t;
}

// psi in sigma x sigma spectral-position layout, 1/16384 folded in.
// Block 0 also fills the w128^{g*k} twiddle table into twg.
__global__ __launch_bounds__(256) void k_psi(const float* __restrict__ mags,
                                             const float* __restrict__ phases,
                                             float2* __restrict__ psi,
                                             float2* __restrict__ twg) {
  if (blockIdx.x == 0 && threadIdx.x < 128) {
    const int gg = threadIdx.x >> 4, k = threadIdx.x & 15;
    float sn, cs;
    __sincosf(-TWO_PI * (float)(gg * k) * (1.0f / 128.0f), &sn, &cs);
    twg[threadIdx.x] = make_float2(cs, sn);
  }
  const int gid = blockIdx.x * 256 + threadIdx.x;      // < 24*16384
  const int p = gid >> 14;
  const int pos = gid & (PLANE - 1);
  const int pr = pos >> 7, pc = pos & 127;
  const int kr = (pr >> 3) + 16 * (pr & 7);            // sigma^-1
  const int kc = (pc >> 3) + 16 * (pc & 7);
  const int src = (p << 14) + kr * SDIM + kc;
  const float m = mags[src] * (1.0f / 16384.0f);
  float sn, cs;
  __sincosf(phases[src], &sn, &cs);
  psi[gid] = make_float2(m * cs, m * sn);
}

// fp32 LDS: Xf feeds everything downstream; this kernel is ~5 us.
__global__ __launch_bounds__(NT) void k_img_fft(const float* __restrict__ img,
                                                float2* __restrict__ Xf,
                                                float* __restrict__ s0,
                                                const float2* __restrict__ twg) {
  __shared__ float2 sC[SDIM * PITCH];
  __shared__ float red[16];
  const int tid = threadIdx.x, b = blockIdx.x;
  const int g = __builtin_amdgcn_readfirstlane(tid >> 7);
  const int q = tid & 127;
  float twr[16], twi[16];
  load_tw(twg, g, twr, twi);
  const float* ip = img + b * PLANE;
  float sum = 0.0f;
#pragma unroll
  for (int kk = 0; kk < 16; ++kk) {
    const int e = tid + kk * NT;
    const float v = ip[e];
    sC[(e >> 7) * PITCH + (e & 127)] = make_float2(v, 0.0f);
    sum += v;
  }
  const float tot = block_reduce_sum(sum, red, tid);   // syncs publish sC
  if (tid == 0) s0[b] = tot * (1.0f / 16384.0f);
  __syncthreads();
  float R[16], I[16];
#pragma unroll
  for (int m = 0; m < 16; ++m) { R[m] = sC[q * PITCH + g + 8 * m].x; I[m] = 0.0f; }
  fwd_fft2(R, I, sC, g, q, twr, twi);
  float2* xp = Xf + b * PLANE;
#pragma unroll
  for (int k2 = 0; k2 < 8; ++k2) {
    const int p1 = (16 * g + k2) * SDIM + q;
    const int p2 = p1 + 8 * SDIM;
    xp[p1] = make_float2(R[k2], I[k2]);
    xp[p2] = make_float2(R[8 + k2], I[8 + k2]);
  }
}

// Phase A: bid<1280: (j1=bid>>8, b=(bid&255)>>2, l1=bid&3):
//   u1=|ifft2(Xf.psi1)|, U=fft2(u1) -> Ubuf (packbf) + s1. bid>=1280: s1 j=5.
__global__ __launch_bounds__(NT) void k_scat_a(const float2* __restrict__ Xf,
                                               const float2* __restrict__ psi,
                                               float* __restrict__ s1num,
                                               unsigned* __restrict__ Ubuf,
                                               const float2* __restrict__ twg) {
  __shared__ unsigned sU[SDIM * PITCH];        // 66 KB -> 2 blocks/CU
  __shared__ float red[16];
  const int tid = threadIdx.x;
  const int g = __builtin_amdgcn_readfirstlane(tid >> 7);
  const int q = tid & 127;
  float twr[16], twi[16];
  load_tw(twg, g, twr, twi);
  const int bid = blockIdx.x;
  float R[16], I[16];

  if (bid < 1280) {
    const int j1 = bid >> 8;
    const int b = (bid & 255) >> 2;
    const int l1 = bid & 3;
    const float2* xp = Xf + b * PLANE;
    const float2* pp = psi + (j1 * 4 + l1) * PLANE;
#pragma unroll
    for (int k2 = 0; k2 < 8; ++k2) {
      const int p1 = (16 * g + k2) * SDIM + q;
      const int p2 = p1 + 8 * SDIM;
      const float2 x1 = xp[p1], v1 = pp[p1];
      const float2 x2 = xp[p2], v2 = pp[p2];
      R[k2] = x1.x * v1.x - x1.y * v1.y;     I[k2] = x1.x * v1.y + x1.y * v1.x;
      R[8 + k2] = x2.x * v2.x - x2.y * v2.y; I[8 + k2] = x2.x * v2.y + x2.y * v2.x;
    }
    inv_fft2<true>(R, I, sU, g, q, twr, twi);
    float s1sum = 0.0f;
#pragma unroll
    for (int m = 0; m < 16; ++m) {
      const float a = fast_sqrtf(R[m] * R[m] + I[m] * I[m]);
      s1sum += a; R[m] = a; I[m] = 0.0f;
    }
    fwd_fft2(R, I, sU, g, q, twr, twi);
    unsigned* up = Ubuf + (size_t)((b * 5 + j1) * 4 + l1) * PLANE;
#pragma unroll
    for (int k2 = 0; k2 < 8; ++k2) {
      const int p1 = (16 * g + k2) * SDIM + q;
      const int p2 = p1 + 8 * SDIM;
      up[p1] = packbf(R[k2], I[k2]);
      up[p2] = packbf(R[8 + k2], I[8 + k2]);
    }
    const float tot = block_reduce_sum(s1sum, red, tid);
    if (tid == 0) atomicAdd(&s1num[b * 6 + j1], tot);
  } else {
    const int idx = bid - 1280;
    const int b = idx >> 2, l = idx & 3;
    const float2* xp = Xf + b * PLANE;
    const float2* pp = psi + (20 + l) * PLANE;
#pragma unroll
    for (int k2 = 0; k2 < 8; ++k2) {
      const int p1 = (16 * g + k2) * SDIM + q;
      const int p2 = p1 + 8 * SDIM;
      const float2 x1 = xp[p1], v1 = pp[p1];
      const float2 x2 = xp[p2], v2 = pp[p2];
      R[k2] = x1.x * v1.x - x1.y * v1.y;     I[k2] = x1.x * v1.y + x1.y * v1.x;
      R[8 + k2] = x2.x * v2.x - x2.y * v2.y; I[8 + k2] = x2.x * v2.y + x2.y * v2.x;
    }
    inv_fft2<true>(R, I, sU, g, q, twr, twi);
    float s = 0.0f;
#pragma unroll
    for (int m = 0; m < 16; ++m) s += fast_sqrtf(R[m] * R[m] + I[m] * I[m]);
    const float tot = block_reduce_sum(s, red, tid);
    if (tid == 0) atomicAdd(&s1num[b * 6 + 5], tot);
  }
}

// Phase B: one inner ifft per block. 15360 blocks (r9 structure: VGPR 32,
// 2 blocks/CU residency is the binding resource -- do NOT hoist U into regs,
// r10 regression).
// idx -> l2 = idx&3; t = idx>>2; pair = t%15; t/=15; l1 = t&3; b = t>>2.
__global__ __launch_bounds__(NT) void k_scat_b(const float2* __restrict__ psi,
                                               const unsigned* __restrict__ Ubuf,
                                               float* __restrict__ s2num,
                                               const float2* __restrict__ twg) {
  __shared__ unsigned sU[SDIM * PITCH];        // 66 KB -> 2 blocks/CU
  __shared__ float red[16];
  const int tid = threadIdx.x;
  const int g = __builtin_amdgcn_readfirstlane(tid >> 7);
  const int q = tid & 127;
  float twr[16], twi[16];
  load_tw(twg, g, twr, twi);
  int t = blockIdx.x;
  const int l2 = t & 3; t >>= 2;
  const int pair = t % 15; t /= 15;
  const int l1 = t & 3;
  const int b = t >> 2;
  int j1 = 0, base = 0;
  if (pair >= 14)      { j1 = 4; base = 14; }
  else if (pair >= 12) { j1 = 3; base = 12; }
  else if (pair >= 9)  { j1 = 2; base = 9; }
  else if (pair >= 5)  { j1 = 1; base = 5; }
  const int j2 = j1 + 1 + (pair - base);
  const unsigned* up = Ubuf + (size_t)((b * 5 + j1) * 4 + l1) * PLANE;
  const float2* pp = psi + (j2 * 4 + l2) * PLANE;
  float R[16], I[16];
#pragma unroll
  for (int k2 = 0; k2 < 8; ++k2) {
    const int p1 = (16 * g + k2) * SDIM + q;
    const int p2 = p1 + 8 * SDIM;
    float ur1, ui1, ur2, ui2;
    unpackbf(up[p1], ur1, ui1);
    unpackbf(up[p2], ur2, ui2);
    const float2 v1 = pp[p1], v2 = pp[p2];
    R[k2] = ur1 * v1.x - ui1 * v1.y;     I[k2] = ur1 * v1.y + ui1 * v1.x;
    R[8 + k2] = ur2 * v2.x - ui2 * v2.y; I[8 + k2] = ur2 * v2.y + ui2 * v2.x;
  }
  inv_fft2<true>(R, I, sU, g, q, twr, twi);
  float vsum = 0.0f;
#pragma unroll
  for (int m = 0; m < 16; ++m) vsum += fast_sqrtf(R[m] * R[m] + I[m] * I[m]);
  const float tot = block_reduce_sum(vsum, red, tid);
  if (tid == 0) atomicAdd(&s2num[b * 15 + pair], tot);
}

// Fallback (ws too small): monolithic, U held in regs (will spill; correctness only).
__global__ __launch_bounds__(NT) void k_scat_mono(const float2* __restrict__ Xf,
                                                  const float2* __restrict__ psi,
                                                  float* __restrict__ s1num,
                                                  float* __restrict__ s2num,
                                                  const float2* __restrict__ twg) {
  __shared__ unsigned sU[SDIM * PITCH];
  __shared__ float red[16];
  const int tid = threadIdx.x;
  const int g = __builtin_amdgcn_readfirstlane(tid >> 7);
  const int q = tid & 127;
  float twr[16], twi[16];
  load_tw(twg, g, twr, twi);
  const int bid = blockIdx.x;
  float R[16], I[16];
  if (bid < 1280) {
    const int j1 = bid >> 8;
    const int b = (bid & 255) >> 2;
    const int l1 = bid & 3;
    const float2* xp = Xf + b * PLANE;
    const float2* pp = psi + (j1 * 4 + l1) * PLANE;
#pragma unroll
    for (int k2 = 0; k2 < 8; ++k2) {
      const int p1 = (16 * g + k2) * SDIM + q;
      const int p2 = p1 + 8 * SDIM;
      const float2 x1 = xp[p1], v1 = pp[p1];
      const float2 x2 = xp[p2], v2 = pp[p2];
      R[k2] = x1.x * v1.x - x1.y * v1.y;     I[k2] = x1.x * v1.y + x1.y * v1.x;
      R[8 + k2] = x2.x * v2.x - x2.y * v2.y; I[8 + k2] = x2.x * v2.y + x2.y * v2.x;
    }
    inv_fft2<true>(R, I, sU, g, q, twr, twi);
    float s1sum = 0.0f;
#pragma unroll
    for (int m = 0; m < 16; ++m) {
      const float a = fast_sqrtf(R[m] * R[m] + I[m] * I[m]);
      s1sum += a; R[m] = a; I[m] = 0.0f;
    }
    fwd_fft2(R, I, sU, g, q, twr, twi);
    float Ur[16], Ui[16];
#pragma unroll
    for (int k = 0; k < 16; ++k) { Ur[k] = R[k]; Ui[k] = I[k]; }
    {
      const float tot = block_reduce_sum(s1sum, red, tid);
      if (tid == 0) atomicAdd(&s1num[b * 6 + j1], tot);
    }
    const int pb = (j1 * (11 - j1)) >> 1;
    int poff = (j1 + 1) * 4 * PLANE;
#pragma unroll 1
    for (int j2 = j1 + 1; j2 <= 5; ++j2) {
      float vsum = 0.0f;
#pragma unroll 1
      for (int l2 = 0; l2 < 4; ++l2) {
#pragma unroll
        for (int k2 = 0; k2 < 8; ++k2) {
          const int p1 = (16 * g + k2) * SDIM + q;
          const int p2i = p1 + 8 * SDIM;
          const float2 v1 = psi[poff + p1], v2 = psi[poff + p2i];
          R[k2] = Ur[k2] * v1.x - Ui[k2] * v1.y;
          I[k2] = Ur[k2] * v1.y + Ui[k2] * v1.x;
          R[8 + k2] = Ur[8 + k2] * v2.x - Ui[8 + k2] * v2.y;
          I[8 + k2] = Ur[8 + k2] * v2.y + Ui[8 + k2] * v2.x;
        }
        inv_fft2<false>(R, I, sU, g, q, twr, twi);
#pragma unroll
        for (int m = 0; m < 16; ++m) vsum += fast_sqrtf(R[m] * R[m] + I[m] * I[m]);
        poff += PLANE;
      }
      const float tot = block_reduce_sum(vsum, red, tid);
      if (tid == 0) atomicAdd(&s2num[b * 15 + pb + (j2 - j1 - 1)], tot);
    }
  } else {
    const int idx = bid - 1280;
    const int b = idx >> 2, l = idx & 3;
    const float2* xp = Xf + b * PLANE;
    const float2* pp = psi + (20 + l) * PLANE;
#pragma unroll
    for (int k2 = 0; k2 < 8; ++k2) {
      const int p1 = (16 * g + k2) * SDIM + q;
      const int p2 = p1 + 8 * SDIM;
      const float2 x1 = xp[p1], v1 = pp[p1];
      const float2 x2 = xp[p2], v2 = pp[p2];
      R[k2] = x1.x * v1.x - x1.y * v1.y;     I[k2] = x1.x * v1.y + x1.y * v1.x;
      R[8 + k2] = x2.x * v2.x - x2.y * v2.y; I[8 + k2] = x2.x * v2.y + x2.y * v2.x;
    }
    inv_fft2<true>(R, I, sU, g, q, twr, twi);
    float s = 0.0f;
#pragma unroll
    for (int m = 0; m < 16; ++m) s += fast_sqrtf(R[m] * R[m] + I[m] * I[m]);
    const float tot = block_reduce_sum(s, red, tid);
    if (tid == 0) atomicAdd(&s1num[b * 6 + 5], tot);
  }
}

__global__ __launch_bounds__(64) void k_final(const float* __restrict__ s0,
                                              const float* __restrict__ s1num,
                                              const float* __restrict__ s2num,
                                              const float* __restrict__ w1,
                                              const float* __restrict__ b1,
                                              const float* __restrict__ w2,
                                              const float* __restrict__ b2,
                                              const float* __restrict__ w3,
                                              const float* __restrict__ b3,
                                              float* __restrict__ out) {
  const int b = threadIdx.x;
  if (b >= 64) return;
  float x[22];
  x[0] = s0[b];
#pragma unroll
  for (int j = 0; j < 6; ++j) x[1 + j] = s1num[b * 6 + j] * (1.0f / (4.0f * 16384.0f));
#pragma unroll
  for (int p = 0; p < 15; ++p) x[7 + p] = s2num[b * 15 + p] * (1.0f / (16.0f * 16384.0f));
  float h1[16];
#pragma unroll
  for (int o = 0; o < 16; ++o) {
    float t = b1[o];
    for (int i = 0; i < 22; ++i) t += x[i] * w1[i * 16 + o];
    h1[o] = fmaxf(t, 0.0f);
  }
  float h2[16];
#pragma unroll
  for (int o = 0; o < 16; ++o) {
    float t = b2[o];
    for (int i = 0; i < 16; ++i) t += h1[i] * w2[i * 16 + o];
    h2[o] = fmaxf(t, 0.0f);
  }
  float t = b3[0];
#pragma unroll
  for (int i = 0; i < 16; ++i) t += h2[i] * w3[i];
  out[b] = 1.0f / (1.0f + expf(-t));
}

extern "C" void kernel_launch(void* const* d_in, const int* in_sizes, int n_in,
                              void* d_out, int out_size, void* d_ws, size_t ws_size,
                              hipStream_t stream) {
  (void)in_sizes; (void)n_in; (void)out_size;
  const float* image  = (const float*)d_in[0];
  const float* mags   = (const float*)d_in[1];
  const float* phases = (const float*)d_in[2];
  const float* w1 = (const float*)d_in[3];
  const float* b1 = (const float*)d_in[4];
  const float* w2 = (const float*)d_in[5];
  const float* b2 = (const float*)d_in[6];
  const float* w3 = (const float*)d_in[7];
  const float* b3 = (const float*)d_in[8];
  float* out = (float*)d_out;

  char* ws = (char*)d_ws;
  float2* psi = (float2*)ws;                       // 3,145,728 B
  float2* Xf  = (float2*)(ws + 3145728);           // 8,388,608 B
  float*  s0  = (float*)(ws + 11534336);           // 64
  float*  s1n = s0 + 64;                           // 384
  float*  s2n = s1n + 384;                         // 960
  float2* twg = (float2*)(s2n + 960);              // 128 float2
  unsigned* Ubuf = (unsigned*)(ws + 11542528);     // 83,886,080 B
  const size_t need = 11542528ull + 83886080ull;   // ~95.4 MB

  hipMemsetAsync(s1n, 0, (384 + 960) * sizeof(float), stream);
  k_psi<<<dim3(1536), dim3(256), 0, stream>>>(mags, phases, psi, twg);
  k_img_fft<<<dim3(64), dim3(NT), 0, stream>>>(image, Xf, s0, twg);
  if (ws_size >= need) {
    k_scat_a<<<dim3(1536), dim3(NT), 0, stream>>>(Xf, psi, s1n, Ubuf, twg);
    k_scat_b<<<dim3(15360), dim3(NT), 0, stream>>>(psi, Ubuf, s2n, twg);
  } else {
    k_scat_mono<<<dim3(1536), dim3(NT), 0, stream>>>(Xf, psi, s1n, s2n, twg);
  }
  k_final<<<dim3(1), dim3(64), 0, stream>>>(s0, s1n, s2n, w1, b1, w2, b2, w3, b3, out);
}